// Round 10
// baseline (38.069 us; speedup 1.0000x reference)
//
#include <hip/hip_runtime.h>
#include <hip/hip_fp16.h>

typedef _Float16 half2_t __attribute__((ext_vector_type(2)));

template<int CTRL>
__device__ __forceinline__ float dpp_add_step(float x) {
    const int p = __builtin_amdgcn_update_dpp(
        0, __builtin_bit_cast(int, x), CTRL, 0xf, 0xf, true);
    return x + __builtin_bit_cast(float, p);
}

// sum across the 8 lanes of a half-group (lanes [8m, 8m+8))
__device__ __forceinline__ float dpp_reduce8(float a) {
    a = dpp_add_step<0xB1>(a);   // quad_perm:[1,0,3,2]  xor 1
    a = dpp_add_step<0x4E>(a);   // quad_perm:[2,3,0,1]  xor 2
    a = dpp_add_step<0x141>(a);  // row_half_mirror   == xor 4 once quad-uniform
    return a;
}

// 8 halfs (one uint4 from LDS) dot 8 halfs of q -> f32, via v_dot2_f32_f16
__device__ __forceinline__ float dot8_fdot2(const uint4 u, const half2_t qh[4]) {
    float a = __builtin_amdgcn_fdot2(qh[0], __builtin_bit_cast(half2_t, u.x), 0.f, false);
    a = __builtin_amdgcn_fdot2(qh[1], __builtin_bit_cast(half2_t, u.y), a, false);
    a = __builtin_amdgcn_fdot2(qh[2], __builtin_bit_cast(half2_t, u.z), a, false);
    a = __builtin_amdgcn_fdot2(qh[3], __builtin_bit_cast(half2_t, u.w), a, false);
    return a;
}

// 8 consecutive halfs (16 B, aligned) from LDS -> two float4
__device__ __forceinline__ void lds_h8(const __half* p, float4& a, float4& b) {
    const uint4 u = *(const uint4*)p;
    const float2 f0 = __half22float2(__builtin_bit_cast(__half2, u.x));
    const float2 f1 = __half22float2(__builtin_bit_cast(__half2, u.y));
    const float2 f2 = __half22float2(__builtin_bit_cast(__half2, u.z));
    const float2 f3 = __half22float2(__builtin_bit_cast(__half2, u.w));
    a = make_float4(f0.x, f0.y, f1.x, f1.y);
    b = make_float4(f2.x, f2.y, f3.x, f3.y);
}

__device__ __forceinline__ float dot8(const float4 q0, const float4 q1,
                                      const float4 a, const float4 b) {
    return q0.x*a.x + q0.y*a.y + q0.z*a.z + q0.w*a.w
         + q1.x*b.x + q1.y*b.y + q1.z*b.z + q1.w*b.w;
}

// Fused no-max softmax (scores ~N(0,1)+bias, exp cannot overflow fp32).
// Lane map: 16-lane group g handles queries base+2g (lanes 0-7) and +1
// (lanes 8-15); each lane owns dims [d8, d8+8) of its own query.
template<bool SAFE>
__device__ __forceinline__ void run_block(
    const float* __restrict__ kh, const float* __restrict__ vh,
    const float* bias, const __half* ksh, const __half* vsh,
    const float4 q0, const float4 q1, const half2_t qh[4],
    const int n, const int ql, const int d8,
    float4& o0, float4& o1, float& l)
{
    constexpr int NEARO[8] = {1, 3, 4, 13, 15, 21, 23, 28};          // idx 0..7
    constexpr int FARO[8]  = {48, 64, 96, 192, 384, 512, 768, 1024}; // idx 8..15
    constexpr float SC = 0.125f * 1.44269504f; // (1/sqrt(64)) * log2(e)

#pragma unroll
    for (int t = 0; t < 8; ++t) {
        // ---- far offset: global gather (L2/L3 resident), fp32 ----
        {
            const int off  = FARO[t];
            const int idx  = n - off;
            const int idxc = SAFE ? (idx < 0 ? 0 : idx) : idx;
            const float4* kp = (const float4*)(kh + ((size_t)idxc << 6) + d8);
            const float4 k0 = kp[0], k1 = kp[1];
            const float4* vp = (const float4*)(vh + ((size_t)idxc << 6) + d8);
            const float4 v0 = vp[0], v1 = vp[1];
            float a = dot8(q0, q1, k0, k1);
            a = dpp_reduce8(a);
            float pw = exp2f(fmaf(a, SC, bias[t + 8]));
            if (SAFE) pw = (idx >= 0) ? pw : 0.f;
            l += pw;
            o0.x += pw*v0.x; o0.y += pw*v0.y; o0.z += pw*v0.z; o0.w += pw*v0.w;
            o1.x += pw*v1.x; o1.y += pw*v1.y; o1.z += pw*v1.z; o1.w += pw*v1.w;
        }
        // ---- near offset: fp16 staged window in LDS, fdot2 k-dot ----
        {
            const int off = NEARO[t];
            const int row = ql + 32 - off;      // in [4, 62]
            const uint4 ku = *(const uint4*)&ksh[(row << 6) + d8];
            float4 v0, v1;
            lds_h8(&vsh[(row << 6) + d8], v0, v1);
            float a = dot8_fdot2(ku, qh);
            a = dpp_reduce8(a);
            float pw = exp2f(fmaf(a, SC, bias[t]));
            if (SAFE) pw = (n - off >= 0) ? pw : 0.f;
            l += pw;
            o0.x += pw*v0.x; o0.y += pw*v0.y; o0.z += pw*v0.z; o0.w += pw*v0.w;
            o1.x += pw*v1.x; o1.y += pw*v1.y; o1.z += pw*v1.z; o1.w += pw*v1.w;
        }
    }
}

__global__ __launch_bounds__(256, 6) void dsqg_attn_kernel(
    const float* __restrict__ q, const float* __restrict__ k,
    const float* __restrict__ v, const float* __restrict__ pb,
    const float* __restrict__ se, float* __restrict__ out)
{
    __shared__ __half ksh[64 * 64];   // near window rows [base-32, base+32)
    __shared__ __half vsh[64 * 64];
    __shared__ __half se_sh[16 * 64]; // scale_embed table, fp16

    // XCD-aware head-major swizzle (XCD x owns heads {2x, 2x+1}, ascending n).
    const int p   = blockIdx.x;
    const int lb_ = ((p & 7) << 8) + (p >> 3);
    const int h   = lb_ >> 7;                       // uniform -> SGPR
    const int nb  = lb_ & 127;
    const int base = nb << 5;

    const int g   = threadIdx.x >> 4;               // group 0..15
    const int j   = threadIdx.x & 15;
    const int sub = j >> 3;                         // 0: query A, 1: query B
    const int d8  = (j & 7) << 3;                   // dim start, lane owns 8 dims
    const int ql  = (g << 1) + sub;                 // local query 0..31
    const int n   = base + ql;
    const size_t hb = (size_t)h << 18;              // h * 4096 * 64

    const float* kh = k + hb;
    const float* vh = v + hb;

    // q: 8 dims of this lane's query (issued early, overlaps staging)
    const float4* qp = (const float4*)(q + hb + ((size_t)n << 6) + d8);
    const float4 q0 = qp[0], q1 = qp[1];

    // stage near k/v window as fp16: each wave stages 16 rows of each
    {
        const int wave = threadIdx.x >> 6;
        const int lane = threadIdx.x & 63;
        const int srow = lane >> 4;
        const int scol = (lane & 15) << 2;
#pragma unroll
        for (int i = 0; i < 4; ++i) {
            const int sr = (wave << 4) + (i << 2) + srow;  // 0..63
            int gr = base - 32 + sr;
            gr = gr < 0 ? 0 : gr;
            const size_t go = ((size_t)gr << 6) + scol;
            const float4 kf = *(const float4*)(kh + go);
            const float4 vf = *(const float4*)(vh + go);
            union { __half2 h2[2]; uint2 u; } pk, pv;
            pk.h2[0] = __floats2half2_rn(kf.x, kf.y);
            pk.h2[1] = __floats2half2_rn(kf.z, kf.w);
            pv.h2[0] = __floats2half2_rn(vf.x, vf.y);
            pv.h2[1] = __floats2half2_rn(vf.z, vf.w);
            *(uint2*)&ksh[(sr << 6) + scol] = pk.u;
            *(uint2*)&vsh[(sr << 6) + scol] = pv.u;
        }
    }
    // stage se as fp16: thread t covers floats [4t, 4t+4)
    {
        const float4 sf = *(const float4*)(se + (threadIdx.x << 2));
        union { __half2 h2[2]; uint2 u; } ps;
        ps.h2[0] = __floats2half2_rn(sf.x, sf.y);
        ps.h2[1] = __floats2half2_rn(sf.z, sf.w);
        *(uint2*)&se_sh[threadIdx.x << 2] = ps.u;
    }

    // q in fp16 for the fdot2 paths
    half2_t qh[4];
    qh[0][0] = (_Float16)q0.x; qh[0][1] = (_Float16)q0.y;
    qh[1][0] = (_Float16)q0.z; qh[1][1] = (_Float16)q0.w;
    qh[2][0] = (_Float16)q1.x; qh[2][1] = (_Float16)q1.y;
    qh[3][0] = (_Float16)q1.z; qh[3][1] = (_Float16)q1.w;

    __syncthreads();

    // bias[i] = pb[i,h]*log2e + (q . se_i)*SC   (reduced over the 8 lanes)
    constexpr float SC = 0.125f * 1.44269504f;
    float bias[16];
#pragma unroll
    for (int i = 0; i < 16; ++i) {
        const uint4 eu = *(const uint4*)&se_sh[(i << 6) + d8];
        float a = dot8_fdot2(eu, qh);
        a = dpp_reduce8(a);
        bias[i] = fmaf(a, SC, pb[(i << 4) + h] * 1.44269504f);
    }

    float l = 0.f;
    float4 o0 = make_float4(0.f, 0.f, 0.f, 0.f);
    float4 o1 = make_float4(0.f, 0.f, 0.f, 0.f);

    if (nb >= 32) {
        run_block<false>(kh, vh, bias, ksh, vsh, q0, q1, qh, n, ql, d8, o0, o1, l);
    } else {
        run_block<true>(kh, vh, bias, ksh, vsh, q0, q1, qh, n, ql, d8, o0, o1, l);
    }

    const float inv = (l > 0.f) ? 1.f / l : 0.f;    // l==0 only at n==0
    o0.x *= inv; o0.y *= inv; o0.z *= inv; o0.w *= inv;
    o1.x *= inv; o1.y *= inv; o1.z *= inv; o1.w *= inv;
    float4* op = (float4*)(out + hb + ((size_t)n << 6) + d8);
    op[0] = o0; op[1] = o1;
}

extern "C" void kernel_launch(void* const* d_in, const int* in_sizes, int n_in,
                              void* d_out, int out_size, void* d_ws, size_t ws_size,
                              hipStream_t stream) {
    const float* q  = (const float*)d_in[0];
    const float* k  = (const float*)d_in[1];
    const float* v  = (const float*)d_in[2];
    const float* pb = (const float*)d_in[3]; // (16 offsets, 16 heads)
    const float* se = (const float*)d_in[4]; // (16 offsets, 64 dims)
    float* out = (float*)d_out;

    dim3 grid(2048);
    dim3 block(256);
    dsqg_attn_kernel<<<grid, block, 0, stream>>>(q, k, v, pb, se, out);
}

// Round 11
// 24.547 us; speedup vs baseline: 1.5508x; 1.5508x over previous
//
#include <hip/hip_runtime.h>
#include <hip/hip_fp16.h>

typedef _Float16 half2_t __attribute__((ext_vector_type(2)));

template<int CTRL>
__device__ __forceinline__ float dpp_add_step(float x) {
    const int p = __builtin_amdgcn_update_dpp(
        0, __builtin_bit_cast(int, x), CTRL, 0xf, 0xf, true);
    return x + __builtin_bit_cast(float, p);
}

// sum across the 8 lanes of a half-group (lanes [8m, 8m+8))
__device__ __forceinline__ float dpp_reduce8(float a) {
    a = dpp_add_step<0xB1>(a);   // quad_perm:[1,0,3,2]  xor 1
    a = dpp_add_step<0x4E>(a);   // quad_perm:[2,3,0,1]  xor 2
    a = dpp_add_step<0x141>(a);  // row_half_mirror   == xor 4 once quad-uniform
    return a;
}

// 8 halfs (one uint4 from LDS) dot 8 halfs of q -> f32, via v_dot2_f32_f16
__device__ __forceinline__ float dot8_fdot2(const uint4 u, const half2_t qh[4]) {
    float a = __builtin_amdgcn_fdot2(qh[0], __builtin_bit_cast(half2_t, u.x), 0.f, false);
    a = __builtin_amdgcn_fdot2(qh[1], __builtin_bit_cast(half2_t, u.y), a, false);
    a = __builtin_amdgcn_fdot2(qh[2], __builtin_bit_cast(half2_t, u.z), a, false);
    a = __builtin_amdgcn_fdot2(qh[3], __builtin_bit_cast(half2_t, u.w), a, false);
    return a;
}

// 8 consecutive halfs (16 B, aligned) from LDS -> two float4
__device__ __forceinline__ void lds_h8(const __half* p, float4& a, float4& b) {
    const uint4 u = *(const uint4*)p;
    const float2 f0 = __half22float2(__builtin_bit_cast(__half2, u.x));
    const float2 f1 = __half22float2(__builtin_bit_cast(__half2, u.y));
    const float2 f2 = __half22float2(__builtin_bit_cast(__half2, u.z));
    const float2 f3 = __half22float2(__builtin_bit_cast(__half2, u.w));
    a = make_float4(f0.x, f0.y, f1.x, f1.y);
    b = make_float4(f2.x, f2.y, f3.x, f3.y);
}

__device__ __forceinline__ float dot8(const float4 q0, const float4 q1,
                                      const float4 a, const float4 b) {
    return q0.x*a.x + q0.y*a.y + q0.z*a.z + q0.w*a.w
         + q1.x*b.x + q1.y*b.y + q1.z*b.z + q1.w*b.w;
}

#define WROWS 96   // LDS window rows: [base-64, base+32)

// Fused no-max softmax (scores ~N(0,1)+bias, exp cannot overflow fp32).
// Lane map: 16-lane group g handles queries base+2g (lanes 0-7) and +1
// (lanes 8-15); each lane owns dims [d8, d8+8) of its own query.
template<bool SAFE>
__device__ __forceinline__ void run_block(
    const float* __restrict__ kh, const float* __restrict__ vh,
    const float* bias, const __half* ksh, const __half* vsh,
    const float4 q0, const float4 q1, const half2_t qh[4],
    const int n, const int ql, const int d8,
    float4& o0, float4& o1, float& l)
{
    constexpr int NEARO[10] = {1, 3, 4, 13, 15, 21, 23, 28, 48, 64};  // idx 0..9
    constexpr int FARO[6]   = {96, 192, 384, 512, 768, 1024};         // idx 10..15
    constexpr float SC = 0.125f * 1.44269504f; // (1/sqrt(64)) * log2(e)

#pragma unroll
    for (int t = 0; t < 10; ++t) {
        // ---- far offset (6): global gather (L2/L3 resident), fp32 ----
        if (t < 6) {
            const int off  = FARO[t];
            const int idx  = n - off;
            const int idxc = SAFE ? (idx < 0 ? 0 : idx) : idx;
            const float4* kp = (const float4*)(kh + ((size_t)idxc << 6) + d8);
            const float4 k0 = kp[0], k1 = kp[1];
            const float4* vp = (const float4*)(vh + ((size_t)idxc << 6) + d8);
            const float4 v0 = vp[0], v1 = vp[1];
            float a = dot8(q0, q1, k0, k1);
            a = dpp_reduce8(a);
            float pw = exp2f(fmaf(a, SC, bias[t + 10]));
            if (SAFE) pw = (idx >= 0) ? pw : 0.f;
            l += pw;
            o0.x += pw*v0.x; o0.y += pw*v0.y; o0.z += pw*v0.z; o0.w += pw*v0.w;
            o1.x += pw*v1.x; o1.y += pw*v1.y; o1.z += pw*v1.z; o1.w += pw*v1.w;
        }
        // ---- near offset (10): fp16 staged window in LDS, fdot2 k-dot ----
        {
            const int off = NEARO[t];
            const int row = ql + 64 - off;      // in [0, 95]
            const uint4 ku = *(const uint4*)&ksh[(row << 6) + d8];
            float4 v0, v1;
            lds_h8(&vsh[(row << 6) + d8], v0, v1);
            float a = dot8_fdot2(ku, qh);
            a = dpp_reduce8(a);
            float pw = exp2f(fmaf(a, SC, bias[t]));
            if (SAFE) pw = (n - off >= 0) ? pw : 0.f;
            l += pw;
            o0.x += pw*v0.x; o0.y += pw*v0.y; o0.z += pw*v0.z; o0.w += pw*v0.w;
            o1.x += pw*v1.x; o1.y += pw*v1.y; o1.z += pw*v1.z; o1.w += pw*v1.w;
        }
    }
}

__global__ __launch_bounds__(256, 4) void dsqg_attn_kernel(
    const float* __restrict__ q, const float* __restrict__ k,
    const float* __restrict__ v, const float* __restrict__ pb,
    const float* __restrict__ se, float* __restrict__ out)
{
    __shared__ __half ksh[WROWS * 64]; // window rows [base-64, base+32), fp16
    __shared__ __half vsh[WROWS * 64];
    __shared__ __half se_sh[16 * 64];  // scale_embed table, fp16

    // XCD-aware head-major swizzle (XCD x owns heads {2x, 2x+1}, ascending n).
    const int p   = blockIdx.x;
    const int lb_ = ((p & 7) << 8) + (p >> 3);
    const int h   = lb_ >> 7;                       // uniform -> SGPR
    const int nb  = lb_ & 127;
    const int base = nb << 5;

    const int g   = threadIdx.x >> 4;               // group 0..15
    const int j   = threadIdx.x & 15;
    const int sub = j >> 3;                         // 0: query A, 1: query B
    const int d8  = (j & 7) << 3;                   // dim start, lane owns 8 dims
    const int ql  = (g << 1) + sub;                 // local query 0..31
    const int n   = base + ql;
    const size_t hb = (size_t)h << 18;              // h * 4096 * 64

    const float* kh = k + hb;
    const float* vh = v + hb;

    // q: 8 dims of this lane's query (issued early, overlaps staging)
    const float4* qp = (const float4*)(q + hb + ((size_t)n << 6) + d8);
    const float4 q0 = qp[0], q1 = qp[1];

    // stage k/v window [base-64, base+32) as fp16: each wave stages 24 rows
    {
        const int wave = threadIdx.x >> 6;
        const int lane = threadIdx.x & 63;
        const int srow = lane >> 4;
        const int scol = (lane & 15) << 2;
#pragma unroll
        for (int i = 0; i < 6; ++i) {
            const int sr = wave * 24 + (i << 2) + srow;  // 0..95
            int gr = base - 64 + sr;
            gr = gr < 0 ? 0 : gr;
            const size_t go = ((size_t)gr << 6) + scol;
            const float4 kf = *(const float4*)(kh + go);
            const float4 vf = *(const float4*)(vh + go);
            union { __half2 h2[2]; uint2 u; } pk, pv;
            pk.h2[0] = __floats2half2_rn(kf.x, kf.y);
            pk.h2[1] = __floats2half2_rn(kf.z, kf.w);
            pv.h2[0] = __floats2half2_rn(vf.x, vf.y);
            pv.h2[1] = __floats2half2_rn(vf.z, vf.w);
            *(uint2*)&ksh[(sr << 6) + scol] = pk.u;
            *(uint2*)&vsh[(sr << 6) + scol] = pv.u;
        }
    }
    // stage se as fp16: thread t covers floats [4t, 4t+4)
    {
        const float4 sf = *(const float4*)(se + (threadIdx.x << 2));
        union { __half2 h2[2]; uint2 u; } ps;
        ps.h2[0] = __floats2half2_rn(sf.x, sf.y);
        ps.h2[1] = __floats2half2_rn(sf.z, sf.w);
        *(uint2*)&se_sh[threadIdx.x << 2] = ps.u;
    }

    // q in fp16 for the fdot2 paths
    half2_t qh[4];
    qh[0][0] = (_Float16)q0.x; qh[0][1] = (_Float16)q0.y;
    qh[1][0] = (_Float16)q0.z; qh[1][1] = (_Float16)q0.w;
    qh[2][0] = (_Float16)q1.x; qh[2][1] = (_Float16)q1.y;
    qh[3][0] = (_Float16)q1.z; qh[3][1] = (_Float16)q1.w;

    __syncthreads();

    // bias[i] = pb[i,h]*log2e + (q . se_i)*SC   (reduced over the 8 lanes)
    constexpr float SC = 0.125f * 1.44269504f;
    float bias[16];
#pragma unroll
    for (int i = 0; i < 16; ++i) {
        const uint4 eu = *(const uint4*)&se_sh[(i << 6) + d8];
        float a = dot8_fdot2(eu, qh);
        a = dpp_reduce8(a);
        bias[i] = fmaf(a, SC, pb[(i << 4) + h] * 1.44269504f);
    }

    float l = 0.f;
    float4 o0 = make_float4(0.f, 0.f, 0.f, 0.f);
    float4 o1 = make_float4(0.f, 0.f, 0.f, 0.f);

    if (nb >= 32) {
        run_block<false>(kh, vh, bias, ksh, vsh, q0, q1, qh, n, ql, d8, o0, o1, l);
    } else {
        run_block<true>(kh, vh, bias, ksh, vsh, q0, q1, qh, n, ql, d8, o0, o1, l);
    }

    const float inv = (l > 0.f) ? 1.f / l : 0.f;    // l==0 only at n==0
    o0.x *= inv; o0.y *= inv; o0.z *= inv; o0.w *= inv;
    o1.x *= inv; o1.y *= inv; o1.z *= inv; o1.w *= inv;
    float4* op = (float4*)(out + hb + ((size_t)n << 6) + d8);
    op[0] = o0; op[1] = o1;
}

extern "C" void kernel_launch(void* const* d_in, const int* in_sizes, int n_in,
                              void* d_out, int out_size, void* d_ws, size_t ws_size,
                              hipStream_t stream) {
    const float* q  = (const float*)d_in[0];
    const float* k  = (const float*)d_in[1];
    const float* v  = (const float*)d_in[2];
    const float* pb = (const float*)d_in[3]; // (16 offsets, 16 heads)
    const float* se = (const float*)d_in[4]; // (16 offsets, 64 dims)
    float* out = (float*)d_out;

    dim3 grid(2048);
    dim3 block(256);
    dsqg_attn_kernel<<<grid, block, 0, stream>>>(q, k, v, pb, se, out);
}